// Round 6
// baseline (13586.896 us; speedup 1.0000x reference)
//
#include <hip/hip_runtime.h>
#include <hip/hip_cooperative_groups.h>
#include <math.h>

// GRU-D (B=128, L=512, DI=128, DM=512) — MI355X persistent scan, online-softmax pooling.
// 128 coop blocks = 2 groups (64 batches) x [32 cell0 + 32 cell1]; each block owns 16
// h-dims, full-K per wave. Inputs runtime-detected f32/bf16; OUTPUT IS FLOAT32 (the
// reference returns f32; expected values are merely bf16-rounded on the harness side).
// Pipeline: inp(t)@ph=t -> c0(t)@t+1 -> c1(t)@t+2 -> pool(t)@t+3 -> soft(t)@t+4; 516 syncs.

namespace cg = cooperative_groups;
typedef __attribute__((ext_vector_type(8))) short short8;
typedef __attribute__((ext_vector_type(4))) float float4v;

#define LOG2E 1.4426950408889634f
#define FLAG_OFF 0
#define XM_OFF   4096      // f32[128*128]
#define VB_OFF   69632     // u32[128*16]
#define INP_OFF  81920     // bf16 2par*128*256
#define H0_OFF   212992    // bf16 2par*128*512
#define H1_OFF   475136    // bf16 4par*128*512
#define SB_OFF   999424    // f32 2par*128

__device__ __forceinline__ unsigned short f2bf(float f) {
  unsigned u = __float_as_uint(f);
  u += 0x7fffu + ((u >> 16) & 1u);
  return (unsigned short)(u >> 16);
}
__device__ __forceinline__ float bf2f(unsigned short h) {
  return __uint_as_float(((unsigned)h) << 16);
}
__device__ __forceinline__ float ldin(const void* p, long i, int bf) {
  return bf ? bf2f(((const unsigned short*)p)[i]) : ((const float*)p)[i];
}
__device__ __forceinline__ int nanbits(float f) {
  return (__float_as_uint(f) & 0x7fffffffu) > 0x7f800000u;
}
__device__ __forceinline__ float sigm(float x){ return 1.f/(1.f+__expf(-x)); }
__device__ __forceinline__ float tanhfast(float x){ return 2.f/(1.f+__expf(-2.f*x)) - 1.f; }
__device__ __forceinline__ float4v mfma16(short8 a, short8 b, float4v c) {
  return __builtin_amdgcn_mfma_f32_16x16x32_bf16(a, b, c, 0, 0, 0);
}

// ---------------- dtype detect ----------------
__global__ __launch_bounds__(256) void k_detect(const void* mask, char* ws) {
  __shared__ int sh[256];
  const unsigned* mw = (const unsigned*)mask;
  int t = threadIdx.x, bad = 0;
  for (int i = t; i < 2048; i += 256) {
    unsigned w = mw[i];
    if (w != 0u && w != 0x3F800000u) bad = 1;
  }
  sh[t] = bad; __syncthreads();
  for (int s = 128; s; s >>= 1) { if (t < s) sh[t] |= sh[t + s]; __syncthreads(); }
  if (t == 0) *(unsigned*)(ws + FLAG_OFF) = sh[0] ? 1u : 0u;
}

// ---------------- prep: xm + valid bits ----------------
__global__ __launch_bounds__(256) void k_prep(const void* x, const void* mask, char* ws) {
  int b = blockIdx.x, tid = threadIdx.x;
  int bf = (int)*(const unsigned*)(ws + FLAG_OFF);
  float* xm = (float*)(ws + XM_OFF);
  unsigned* vb = (unsigned*)(ws + VB_OFF);
  __shared__ int va[2][512];
  int wav = tid >> 6, lane = tid & 63;
  if (tid < 128) {
    float sx = 0.f, sm = 0.f;
    for (int l = 0; l < 512; ++l) {
      long idx = ((long)b*512 + l)*128 + tid;
      float xv = ldin(x, idx, bf); if (nanbits(xv)) xv = 0.f;
      float mv = ldin(mask, idx, bf);
      sx += xv*mv; sm += mv;
      int any = (__ballot(mv > 0.f) != 0ull);
      if (lane == 0) va[wav][l] = any;
    }
    xm[b*128 + tid] = sx / fmaxf(sm, 1.f);
  }
  __syncthreads();
  if (tid < 16) {
    unsigned w = 0;
    for (int j = 0; j < 32; ++j) { int l = tid*32 + j; if (va[0][l] | va[1][l]) w |= (1u << j); }
    vb[b*16 + tid] = w;
  }
}

// ---------------- scan ----------------
struct SC0 { unsigned short wgi[3*8*64*8]; unsigned short wgh[3*16*64*8]; };           // 72 KB
struct SC1 { unsigned short w1i[3*16*64*8]; unsigned short w1h[3*16*64*8];
             unsigned short pwl[16*64*8]; float w2[512]; float pbl[16], pul[16]; };    // ~114 KB
union __align__(16) SMU { SC0 c0; SC1 c1; };

__global__ __launch_bounds__(256, 1) void k_scan(
    const void* x, const void* tau, const void* mask,
    const void* W_gx, const void* W_gh,
    const void* Wih0, const void* Whh0, const void* bih0, const void* bhh0,
    const void* Wih1, const void* Whh1, const void* bih1, const void* bhh1,
    const void* pW, const void* pb, const void* pu,
    const void* mw, const void* mb, const void* lw, const void* lb,
    char* ws, float* out)
{
  cg::grid_group gg = cg::this_grid();
  __shared__ SMU sm;
  int tid = threadIdx.x, bx = blockIdx.x;
  int g = bx & 1, role = bx >> 1;          // 2 groups of 64 batches
  int wav = tid >> 6, lane = tid & 63, quad = lane >> 4, l15 = lane & 15;
  int bf = (int)*(const unsigned*)(ws + FLAG_OFF);
  float* xm = (float*)(ws + XM_OFF);
  unsigned* vb = (unsigned*)(ws + VB_OFF);
  unsigned short* INP = (unsigned short*)(ws + INP_OFF);
  unsigned short* H0  = (unsigned short*)(ws + H0_OFF);
  unsigned short* H1  = (unsigned short*)(ws + H1_OFF);
  float* SB = (float*)(ws + SB_OFF);

  bool isC0 = (role < 32);
  int su = isC0 ? role : (role - 32);      // 16 h-dims: [16su, 16su+16)
  int bg = 64*g + 16*wav + l15;            // this lane's batch (GEMM n-dim)
  bool isSoft = isC0 && (su < 4);
  bool isPool = (!isC0) && (su < 16);

  float biasR[4], biasZ[4], biasNI[4], biasNH[4], w2own[4];
  float hloc[4] = {0.f,0.f,0.f,0.f};
  float softM = -INFINITY, softDen = 0.f;
  float num[32];
  #pragma unroll
  for (int j = 0; j < 32; ++j) num[j] = 0.f;
  int sb_b = 64*g + 16*su + (tid >> 4);    // soft: batch (su<4)
  int sd0 = (tid & 15) * 32;               // soft: dim slice base

  float xprev = 0.f, xm_r = 0.f, gxw2 = 0.f;
  int b_xi = 64*g + (tid >> 2), f_xi = 4*su + (tid & 3);   // impute mapping (c0)

  if (isC0) {
    for (int r = 0; r < 4; ++r) {
      int row = 16*su + 4*quad + r;
      biasR[r]  = ldin(bih0, row, bf) + ldin(bhh0, row, bf);
      biasZ[r]  = ldin(bih0, 512+row, bf) + ldin(bhh0, 512+row, bf);
      biasNI[r] = ldin(bih0, 1024+row, bf);
      biasNH[r] = ldin(bhh0, 1024+row, bf);
      w2own[r] = 0.f;
    }
    xm_r = xm[b_xi*128 + f_xi];
    gxw2 = fmaxf(ldin(W_gx, f_xi, bf), 0.f) * LOG2E;
    for (int i = tid; i < 3*8*64; i += 256) {
      int gate = i >> 9, rr = i & 511, kt = rr >> 6, ll = rr & 63;
      int row = gate*512 + 16*su + (ll & 15);
      int k0 = kt*32 + (ll >> 4)*8;
      for (int j = 0; j < 8; ++j) sm.c0.wgi[i*8+j] = f2bf(ldin(Wih0, (long)row*256 + k0 + j, bf));
    }
    for (int i = tid; i < 3*16*64; i += 256) {
      int gate = i >> 10, rr = i & 1023, kt = rr >> 6, ll = rr & 63;
      int row = gate*512 + 16*su + (ll & 15);
      int k0 = kt*32 + (ll >> 4)*8;
      for (int j = 0; j < 8; ++j) sm.c0.wgh[i*8+j] = f2bf(ldin(Whh0, (long)row*512 + k0 + j, bf));
    }
    if (isSoft) SB[tid] = 0.f;   // zero both parities (redundant across soft blocks, same value)
  } else {
    for (int r = 0; r < 4; ++r) {
      int row = 16*su + 4*quad + r;
      biasR[r]  = ldin(bih1, row, bf) + ldin(bhh1, row, bf);
      biasZ[r]  = ldin(bih1, 512+row, bf) + ldin(bhh1, 512+row, bf);
      biasNI[r] = ldin(bih1, 1024+row, bf);
      biasNH[r] = ldin(bhh1, 1024+row, bf);
      w2own[r]  = fmaxf(ldin(W_gh, row, bf), 0.f) * LOG2E;
    }
    for (int i = tid; i < 3*16*64; i += 256) {
      int gate = i >> 10, rr = i & 1023, kt = rr >> 6, ll = rr & 63;
      int row = gate*512 + 16*su + (ll & 15);
      int k0 = kt*32 + (ll >> 4)*8;
      for (int j = 0; j < 8; ++j) {
        sm.c1.w1i[i*8+j] = f2bf(ldin(Wih1, (long)row*512 + k0 + j, bf));
        sm.c1.w1h[i*8+j] = f2bf(ldin(Whh1, (long)row*512 + k0 + j, bf));
      }
    }
    for (int i = tid; i < 512; i += 256) sm.c1.w2[i] = fmaxf(ldin(W_gh, i, bf), 0.f) * LOG2E;
    if (isPool) {
      for (int i = tid; i < 16*64; i += 256) {
        int kt = i >> 6, ll = i & 63;
        int row = 16*su + (ll & 15);
        int k0 = kt*32 + (ll >> 4)*8;
        for (int j = 0; j < 8; ++j) sm.c1.pwl[i*8+j] = f2bf(ldin(pW, (long)row*512 + k0 + j, bf));
      }
      if (tid < 16) { sm.c1.pbl[tid] = ldin(pb, 16*su + tid, bf); sm.c1.pul[tid] = ldin(pu, 16*su + tid, bf); }
    }
  }
  __syncthreads();

  for (int ph = 0; ph < 516; ++ph) {
    if (isC0) {
      if (ph < 512) {              // impute + publish x_imp(t=ph), mask(t=ph)
        float dt = ldin(tau, (long)b_xi*512 + ph, bf);
        long idx = ((long)b_xi*512 + ph)*128 + f_xi;
        float xv = ldin(x, idx, bf); if (nanbits(xv)) xv = 0.f;
        float mv = ldin(mask, idx, bf);
        float gxv = exp2f(-dt * gxw2);
        float xi = mv*xv + (1.f-mv)*(gxv*xprev + (1.f-gxv)*xm_r);
        xprev = xi;
        unsigned short* ip = INP + ((long)(ph & 1)*128 + b_xi)*256;
        ip[f_xi] = f2bf(xi);
        ip[128 + f_xi] = f2bf(mv);
      }
      if (ph >= 1 && ph <= 512) {  // cell0 step t0 = ph-1, full K per wave
        int parR = (ph-1) & 1;
        const unsigned short* inpP = INP + ((long)parR*128 + bg)*256 + quad*8;
        const unsigned short* h0P  = H0 + ((long)parR*128 + bg)*512 + quad*8;
        float4v aR={}, aZ={}, aNI={}, aNH={};
        #pragma unroll
        for (int kt = 0; kt < 8; ++kt) {
          short8 Bi = *(const short8*)(inpP + kt*32);
          short8 Ar = *(const short8*)&sm.c0.wgi[((0*8+kt)*64+lane)*8];
          short8 Az = *(const short8*)&sm.c0.wgi[((1*8+kt)*64+lane)*8];
          short8 An = *(const short8*)&sm.c0.wgi[((2*8+kt)*64+lane)*8];
          aR = mfma16(Ar,Bi,aR); aZ = mfma16(Az,Bi,aZ); aNI = mfma16(An,Bi,aNI);
        }
        if (ph > 1) {
          #pragma unroll
          for (int kt = 0; kt < 16; ++kt) {
            short8 Bh = *(const short8*)(h0P + kt*32);
            short8 Ar = *(const short8*)&sm.c0.wgh[((0*16+kt)*64+lane)*8];
            short8 Az = *(const short8*)&sm.c0.wgh[((1*16+kt)*64+lane)*8];
            short8 An = *(const short8*)&sm.c0.wgh[((2*16+kt)*64+lane)*8];
            aR = mfma16(Ar,Bh,aR); aZ = mfma16(Az,Bh,aZ); aNH = mfma16(An,Bh,aNH);
          }
        }
        unsigned short hb[4];
        #pragma unroll
        for (int r = 0; r < 4; ++r) {
          float rg = sigm(aR[r] + biasR[r]);
          float zg = sigm(aZ[r] + biasZ[r]);
          float ng = tanhfast(aNI[r] + biasNI[r] + rg*(aNH[r] + biasNH[r]));
          float hn = (1.f - zg)*ng + zg*hloc[r];
          hloc[r] = hn; hb[r] = f2bf(hn);
        }
        unsigned short* dst = H0 + ((long)(ph & 1)*128 + bg)*512 + 16*su + 4*quad;
        uint2 pk; pk.x = hb[0] | ((unsigned)hb[1] << 16); pk.y = hb[2] | ((unsigned)hb[3] << 16);
        *(uint2*)dst = pk;
      }
      if (isSoft && ph >= 4) {     // online softmax, t_s = ph-4 (16 thr/batch x 32 dims)
        int ts = ph - 4;
        float s = SB[(ts & 1)*128 + sb_b];
        unsigned vbit = (vb[sb_b*16 + (ts >> 5)] >> (ts & 31)) & 1u;
        __threadfence_block();     // ensure the load above completed before same-address store
        if ((tid & 15) == 0) SB[(ts & 1)*128 + sb_b] = 0.f;
        if (vbit) {
          float Mn = fmaxf(softM, s);
          float al = __expf(softM - Mn);
          float e  = __expf(s - Mn);
          const unsigned short* hp = H1 + ((long)((ts+2) & 3)*128 + sb_b)*512 + sd0;
          softDen = softDen*al + e;
          #pragma unroll
          for (int v = 0; v < 4; ++v) {
            short8 hv = *(const short8*)(hp + v*8);
            #pragma unroll
            for (int ee = 0; ee < 8; ++ee)
              num[v*8+ee] = num[v*8+ee]*al + e*bf2f((unsigned short)hv[ee]);
          }
          softM = Mn;
        }
      }
    } else {
      if (ph >= 2 && ph <= 513) {  // cell1 step t1 = ph-2, full K per wave
        int t1 = ph - 2;
        int parH = (ph-1) & 1, parH1 = (ph-1) & 3;
        const unsigned short* h0P = H0 + ((long)parH*128 + bg)*512 + quad*8;
        float dtb = ldin(tau, (long)bg*512 + t1, bf);
        float4v aR={}, aZ={}, aNI={}, aNH={};
        #pragma unroll
        for (int kt = 0; kt < 16; ++kt) {
          short8 Bi = *(const short8*)(h0P + kt*32);
          short8 Ar = *(const short8*)&sm.c1.w1i[((0*16+kt)*64+lane)*8];
          short8 Az = *(const short8*)&sm.c1.w1i[((1*16+kt)*64+lane)*8];
          short8 An = *(const short8*)&sm.c1.w1i[((2*16+kt)*64+lane)*8];
          aR = mfma16(Ar,Bi,aR); aZ = mfma16(Az,Bi,aZ); aNI = mfma16(An,Bi,aNI);
        }
        if (t1 >= 1) {
          const unsigned short* h1P = H1 + ((long)parH1*128 + bg)*512 + quad*8;
          #pragma unroll
          for (int kt = 0; kt < 16; ++kt) {
            short8 hv = *(const short8*)(h1P + kt*32);
            const float* w2p = &sm.c1.w2[kt*32 + quad*8];
            short8 Bh;
            #pragma unroll
            for (int e = 0; e < 8; ++e) {
              float f = bf2f((unsigned short)hv[e]) * exp2f(-dtb * w2p[e]);
              Bh[e] = (short)f2bf(f);
            }
            short8 Ar = *(const short8*)&sm.c1.w1h[((0*16+kt)*64+lane)*8];
            short8 Az = *(const short8*)&sm.c1.w1h[((1*16+kt)*64+lane)*8];
            short8 An = *(const short8*)&sm.c1.w1h[((2*16+kt)*64+lane)*8];
            aR = mfma16(Ar,Bh,aR); aZ = mfma16(Az,Bh,aZ); aNH = mfma16(An,Bh,aNH);
          }
        }
        unsigned short hb[4];
        #pragma unroll
        for (int r = 0; r < 4; ++r) {
          float rg = sigm(aR[r] + biasR[r]);
          float zg = sigm(aZ[r] + biasZ[r]);
          float ng = tanhfast(aNI[r] + biasNI[r] + rg*(aNH[r] + biasNH[r]));
          float h1d = exp2f(-dtb * w2own[r]) * hloc[r];
          float hn = (1.f - zg)*ng + zg*h1d;
          hloc[r] = hn; hb[r] = f2bf(hn);
        }
        unsigned short* dst = H1 + ((long)(ph & 3)*128 + bg)*512 + 16*su + 4*quad;
        uint2 pk; pk.x = hb[0] | ((unsigned)hb[1] << 16); pk.y = hb[2] | ((unsigned)hb[3] << 16);
        *(uint2*)dst = pk;
      }
      if (isPool && ph >= 3 && ph <= 514) {   // pool partial, t = ph-3
        int t = ph - 3, parP = (ph-1) & 3;
        const unsigned short* hP = H1 + ((long)parP*128 + bg)*512 + quad*8;
        float4v pa = {};
        #pragma unroll
        for (int kt = 0; kt < 16; ++kt) {
          short8 Bv = *(const short8*)(hP + kt*32);
          short8 Av = *(const short8*)&sm.c1.pwl[(kt*64+lane)*8];
          pa = mfma16(Av, Bv, pa);
        }
        float part = 0.f;
        #pragma unroll
        for (int r = 0; r < 4; ++r)
          part += sm.c1.pul[4*quad+r] * tanhfast(pa[r] + sm.c1.pbl[4*quad+r]);
        part += __shfl_down(part, 32);
        part += __shfl_down(part, 16);
        if (lane < 16) atomicAdd(&SB[(t & 1)*128 + bg], part);
      }
    }
    gg.sync();
  }

  if (isSoft) {   // heads: z = num/den; mort = z@mw.T + mb, los = z@lw.T + lb  (f32 out!)
    float invd = 1.f / fmaxf(softDen, 1e-30f);
    float m0 = 0.f, m1 = 0.f, l0 = 0.f;
    #pragma unroll
    for (int j = 0; j < 32; ++j) {
      float z = num[j] * invd;
      m0 += z * ldin(mw, sd0 + j, bf);
      m1 += z * ldin(mw, 512 + sd0 + j, bf);
      l0 += z * ldin(lw, sd0 + j, bf);
    }
    for (int off = 8; off; off >>= 1) {
      m0 += __shfl_down(m0, off, 16);
      m1 += __shfl_down(m1, off, 16);
      l0 += __shfl_down(l0, off, 16);
    }
    if ((tid & 15) == 0) {
      out[2*sb_b]     = m0 + ldin(mb, 0, bf);
      out[2*sb_b + 1] = m1 + ldin(mb, 1, bf);
      out[256 + sb_b] = l0 + ldin(lb, 0, bf);
    }
  }
}

extern "C" void kernel_launch(void* const* d_in, const int* in_sizes, int n_in,
                              void* d_out, int out_size, void* d_ws, size_t ws_size,
                              hipStream_t stream) {
  const void* x    = d_in[0];
  const void* tau  = d_in[1];
  const void* mask = d_in[2];
  const void* W_gx = d_in[3];
  const void* W_gh = d_in[4];
  const void* Wih0 = d_in[5];
  const void* Whh0 = d_in[6];
  const void* bih0 = d_in[7];
  const void* bhh0 = d_in[8];
  const void* Wih1 = d_in[9];
  const void* Whh1 = d_in[10];
  const void* bih1 = d_in[11];
  const void* bhh1 = d_in[12];
  const void* pW   = d_in[13];
  const void* pb   = d_in[14];
  const void* pu   = d_in[15];
  const void* mw   = d_in[16];
  const void* mb   = d_in[17];
  const void* lw   = d_in[18];
  const void* lb   = d_in[19];
  (void)in_sizes; (void)n_in; (void)out_size; (void)ws_size;
  char* ws = (char*)d_ws;
  float* outp = (float*)d_out;

  hipLaunchKernelGGL(k_detect, dim3(1), dim3(256), 0, stream, mask, ws);
  hipLaunchKernelGGL(k_prep, dim3(128), dim3(256), 0, stream, x, mask, ws);

  void* kargs[] = {
    (void*)&x, (void*)&tau, (void*)&mask, (void*)&W_gx, (void*)&W_gh,
    (void*)&Wih0, (void*)&Whh0, (void*)&bih0, (void*)&bhh0,
    (void*)&Wih1, (void*)&Whh1, (void*)&bih1, (void*)&bhh1,
    (void*)&pW, (void*)&pb, (void*)&pu, (void*)&mw, (void*)&mb,
    (void*)&lw, (void*)&lb, (void*)&ws, (void*)&outp
  };
  hipLaunchCooperativeKernel((void*)k_scan, dim3(128), dim3(256), kargs, 0, stream);
}

// Round 7
// 8744.645 us; speedup vs baseline: 1.5537x; 1.5537x over previous
//
#include <hip/hip_runtime.h>
#include <math.h>

// GRU-D (B=128, L=512, DI=128, DM=512) — MI355X persistent scan, online-softmax pooling.
// 128 coop blocks = 2 independent groups (64 batches each) x [32 cell0 + 32 cell1].
// R6 passing compute, with: hand-rolled per-group 64-block barrier (agent-scope fences,
// no system flush), atomicExch SB read-zero, and next-phase x/mask/tau prefetch.
// Pipeline: inp(t)@ph=t -> c0(t)@t+1 -> c1(t)@t+2 -> pool(t)@t+3 -> soft(t)@t+4; 516 phases.

typedef __attribute__((ext_vector_type(8))) short short8;
typedef __attribute__((ext_vector_type(4))) float float4v;

#define LOG2E 1.4426950408889634f
#define FLAG_OFF 0
#define CTR_OFF  1024      // u32 ctr[g] at CTR_OFF + g*256B
#define XM_OFF   4096      // f32[128*128]
#define VB_OFF   69632     // u32[128*16]
#define INP_OFF  81920     // bf16 2par*128*256
#define H0_OFF   212992    // bf16 2par*128*512
#define H1_OFF   475136    // bf16 4par*128*512
#define SB_OFF   999424    // f32 2par*128

__device__ __forceinline__ unsigned short f2bf(float f) {
  unsigned u = __float_as_uint(f);
  u += 0x7fffu + ((u >> 16) & 1u);
  return (unsigned short)(u >> 16);
}
__device__ __forceinline__ float bf2f(unsigned short h) {
  return __uint_as_float(((unsigned)h) << 16);
}
__device__ __forceinline__ float ldin(const void* p, long i, int bf) {
  return bf ? bf2f(((const unsigned short*)p)[i]) : ((const float*)p)[i];
}
__device__ __forceinline__ int nanbits(float f) {
  return (__float_as_uint(f) & 0x7fffffffu) > 0x7f800000u;
}
__device__ __forceinline__ float sigm(float x){ return 1.f/(1.f+__expf(-x)); }
__device__ __forceinline__ float tanhfast(float x){ return 2.f/(1.f+__expf(-2.f*x)) - 1.f; }
__device__ __forceinline__ float4v mfma16(short8 a, short8 b, float4v c) {
  return __builtin_amdgcn_mfma_f32_16x16x32_bf16(a, b, c, 0, 0, 0);
}
// per-group barrier: 64 blocks, agent-scope fences only (no system-scope L2 flush)
__device__ __forceinline__ void gbar(unsigned* ctr, int tid, unsigned tgt) {
  __syncthreads();
  if (tid == 0) {
    __threadfence();
    __hip_atomic_fetch_add(ctr, 1u, __ATOMIC_RELAXED, __HIP_MEMORY_SCOPE_AGENT);
    while (__hip_atomic_load(ctr, __ATOMIC_RELAXED, __HIP_MEMORY_SCOPE_AGENT) < tgt)
      __builtin_amdgcn_s_sleep(1);
    __threadfence();
  }
  __syncthreads();
}

// ---------------- dtype detect + ctr zero ----------------
__global__ __launch_bounds__(256) void k_detect(const void* mask, char* ws) {
  __shared__ int sh[256];
  const unsigned* mw = (const unsigned*)mask;
  int t = threadIdx.x, bad = 0;
  for (int i = t; i < 2048; i += 256) {
    unsigned w = mw[i];
    if (w != 0u && w != 0x3F800000u) bad = 1;
  }
  sh[t] = bad; __syncthreads();
  for (int s = 128; s; s >>= 1) { if (t < s) sh[t] |= sh[t + s]; __syncthreads(); }
  if (t == 0) *(unsigned*)(ws + FLAG_OFF) = sh[0] ? 1u : 0u;
  if (t < 128) ((unsigned*)(ws + CTR_OFF))[t] = 0u;
}

// ---------------- prep: xm + valid bits ----------------
__global__ __launch_bounds__(256) void k_prep(const void* x, const void* mask, char* ws) {
  int b = blockIdx.x, tid = threadIdx.x;
  int bf = (int)*(const unsigned*)(ws + FLAG_OFF);
  float* xm = (float*)(ws + XM_OFF);
  unsigned* vb = (unsigned*)(ws + VB_OFF);
  __shared__ int va[2][512];
  int wav = tid >> 6, lane = tid & 63;
  if (tid < 128) {
    float sx = 0.f, sm = 0.f;
    for (int l = 0; l < 512; ++l) {
      long idx = ((long)b*512 + l)*128 + tid;
      float xv = ldin(x, idx, bf); if (nanbits(xv)) xv = 0.f;
      float mv = ldin(mask, idx, bf);
      sx += xv*mv; sm += mv;
      int any = (__ballot(mv > 0.f) != 0ull);
      if (lane == 0) va[wav][l] = any;
    }
    xm[b*128 + tid] = sx / fmaxf(sm, 1.f);
  }
  __syncthreads();
  if (tid < 16) {
    unsigned w = 0;
    for (int j = 0; j < 32; ++j) { int l = tid*32 + j; if (va[0][l] | va[1][l]) w |= (1u << j); }
    vb[b*16 + tid] = w;
  }
}

// ---------------- scan ----------------
struct SC0 { unsigned short wgi[3*8*64*8]; unsigned short wgh[3*16*64*8]; };           // 72 KB
struct SC1 { unsigned short w1i[3*16*64*8]; unsigned short w1h[3*16*64*8];
             unsigned short pwl[16*64*8]; float w2[512]; float pbl[16], pul[16]; };    // ~114 KB
union __align__(16) SMU { SC0 c0; SC1 c1; };

__global__ __launch_bounds__(256, 1) void k_scan(
    const void* x, const void* tau, const void* mask,
    const void* W_gx, const void* W_gh,
    const void* Wih0, const void* Whh0, const void* bih0, const void* bhh0,
    const void* Wih1, const void* Whh1, const void* bih1, const void* bhh1,
    const void* pW, const void* pb, const void* pu,
    const void* mw, const void* mb, const void* lw, const void* lb,
    char* ws, float* out)
{
  __shared__ SMU sm;
  int tid = threadIdx.x, bx = blockIdx.x;
  int g = bx & 1, role = bx >> 1;          // 2 groups of 64 batches
  int wav = tid >> 6, lane = tid & 63, quad = lane >> 4, l15 = lane & 15;
  int bf = (int)*(const unsigned*)(ws + FLAG_OFF);
  unsigned* myctr = (unsigned*)(ws + CTR_OFF) + g*64;
  float* xm = (float*)(ws + XM_OFF);
  unsigned* vb = (unsigned*)(ws + VB_OFF);
  unsigned short* INP = (unsigned short*)(ws + INP_OFF);
  unsigned short* H0  = (unsigned short*)(ws + H0_OFF);
  unsigned short* H1  = (unsigned short*)(ws + H1_OFF);
  float* SB = (float*)(ws + SB_OFF);

  bool isC0 = (role < 32);
  int su = isC0 ? role : (role - 32);      // 16 h-dims: [16su, 16su+16)
  int bg = 64*g + 16*wav + l15;            // this lane's batch (GEMM n-dim)
  bool isSoft = isC0 && (su < 4);
  bool isPool = (!isC0) && (su < 16);

  float biasR[4], biasZ[4], biasNI[4], biasNH[4], w2own[4];
  float hloc[4] = {0.f,0.f,0.f,0.f};
  float softM = -INFINITY, softDen = 0.f;
  float num[32];
  #pragma unroll
  for (int j = 0; j < 32; ++j) num[j] = 0.f;
  int sb_b = 64*g + 16*su + (tid >> 4);    // soft: batch (su<4)
  int sd0 = (tid & 15) * 32;               // soft: dim slice base

  float xprev = 0.f, xm_r = 0.f, gxw2 = 0.f;
  int b_xi = 64*g + (tid >> 2), f_xi = 4*su + (tid & 3);   // impute mapping (c0)
  float dt_n = 0.f, xv_n = 0.f, mv_n = 0.f, dtb_n = 0.f;   // prefetch regs

  if (isC0) {
    for (int r = 0; r < 4; ++r) {
      int row = 16*su + 4*quad + r;
      biasR[r]  = ldin(bih0, row, bf) + ldin(bhh0, row, bf);
      biasZ[r]  = ldin(bih0, 512+row, bf) + ldin(bhh0, 512+row, bf);
      biasNI[r] = ldin(bih0, 1024+row, bf);
      biasNH[r] = ldin(bhh0, 1024+row, bf);
      w2own[r] = 0.f;
    }
    xm_r = xm[b_xi*128 + f_xi];
    gxw2 = fmaxf(ldin(W_gx, f_xi, bf), 0.f) * LOG2E;
    for (int i = tid; i < 3*8*64; i += 256) {
      int gate = i >> 9, rr = i & 511, kt = rr >> 6, ll = rr & 63;
      int row = gate*512 + 16*su + (ll & 15);
      int k0 = kt*32 + (ll >> 4)*8;
      for (int j = 0; j < 8; ++j) sm.c0.wgi[i*8+j] = f2bf(ldin(Wih0, (long)row*256 + k0 + j, bf));
    }
    for (int i = tid; i < 3*16*64; i += 256) {
      int gate = i >> 10, rr = i & 1023, kt = rr >> 6, ll = rr & 63;
      int row = gate*512 + 16*su + (ll & 15);
      int k0 = kt*32 + (ll >> 4)*8;
      for (int j = 0; j < 8; ++j) sm.c0.wgh[i*8+j] = f2bf(ldin(Whh0, (long)row*512 + k0 + j, bf));
    }
    if (isSoft) SB[tid] = 0.f;   // zero both parities (redundant across soft blocks, same value)
    // prefetch t=0 impute inputs
    dt_n = ldin(tau, (long)b_xi*512, bf);
    long idx0 = (long)b_xi*512*128 + f_xi;
    xv_n = ldin(x, idx0, bf);
    mv_n = ldin(mask, idx0, bf);
  } else {
    for (int r = 0; r < 4; ++r) {
      int row = 16*su + 4*quad + r;
      biasR[r]  = ldin(bih1, row, bf) + ldin(bhh1, row, bf);
      biasZ[r]  = ldin(bih1, 512+row, bf) + ldin(bhh1, 512+row, bf);
      biasNI[r] = ldin(bih1, 1024+row, bf);
      biasNH[r] = ldin(bhh1, 1024+row, bf);
      w2own[r]  = fmaxf(ldin(W_gh, row, bf), 0.f) * LOG2E;
    }
    for (int i = tid; i < 3*16*64; i += 256) {
      int gate = i >> 10, rr = i & 1023, kt = rr >> 6, ll = rr & 63;
      int row = gate*512 + 16*su + (ll & 15);
      int k0 = kt*32 + (ll >> 4)*8;
      for (int j = 0; j < 8; ++j) {
        sm.c1.w1i[i*8+j] = f2bf(ldin(Wih1, (long)row*512 + k0 + j, bf));
        sm.c1.w1h[i*8+j] = f2bf(ldin(Whh1, (long)row*512 + k0 + j, bf));
      }
    }
    for (int i = tid; i < 512; i += 256) sm.c1.w2[i] = fmaxf(ldin(W_gh, i, bf), 0.f) * LOG2E;
    if (isPool) {
      for (int i = tid; i < 16*64; i += 256) {
        int kt = i >> 6, ll = i & 63;
        int row = 16*su + (ll & 15);
        int k0 = kt*32 + (ll >> 4)*8;
        for (int j = 0; j < 8; ++j) sm.c1.pwl[i*8+j] = f2bf(ldin(pW, (long)row*512 + k0 + j, bf));
      }
      if (tid < 16) { sm.c1.pbl[tid] = ldin(pb, 16*su + tid, bf); sm.c1.pul[tid] = ldin(pu, 16*su + tid, bf); }
    }
    dtb_n = ldin(tau, (long)bg*512, bf);   // prefetch t1=0
  }
  __syncthreads();

  for (int ph = 0; ph < 516; ++ph) {
    if (isC0) {
      if (ph < 512) {              // impute + publish x_imp(t=ph), mask(t=ph)
        float dt = dt_n, xv = xv_n, mv = mv_n;
        if (ph + 1 < 512) {        // prefetch t=ph+1 (latency hidden behind next barrier)
          dt_n = ldin(tau, (long)b_xi*512 + ph + 1, bf);
          long idx2 = ((long)b_xi*512 + (ph+1))*128 + f_xi;
          xv_n = ldin(x, idx2, bf);
          mv_n = ldin(mask, idx2, bf);
        }
        if (nanbits(xv)) xv = 0.f;
        float gxv = exp2f(-dt * gxw2);
        float xi = mv*xv + (1.f-mv)*(gxv*xprev + (1.f-gxv)*xm_r);
        xprev = xi;
        unsigned short* ip = INP + ((long)(ph & 1)*128 + b_xi)*256;
        ip[f_xi] = f2bf(xi);
        ip[128 + f_xi] = f2bf(mv);
      }
      if (ph >= 1 && ph <= 512) {  // cell0 step t0 = ph-1, full K per wave
        int parR = (ph-1) & 1;
        const unsigned short* inpP = INP + ((long)parR*128 + bg)*256 + quad*8;
        const unsigned short* h0P  = H0 + ((long)parR*128 + bg)*512 + quad*8;
        float4v aR={}, aZ={}, aNI={}, aNH={};
        #pragma unroll
        for (int kt = 0; kt < 8; ++kt) {
          short8 Bi = *(const short8*)(inpP + kt*32);
          short8 Ar = *(const short8*)&sm.c0.wgi[((0*8+kt)*64+lane)*8];
          short8 Az = *(const short8*)&sm.c0.wgi[((1*8+kt)*64+lane)*8];
          short8 An = *(const short8*)&sm.c0.wgi[((2*8+kt)*64+lane)*8];
          aR = mfma16(Ar,Bi,aR); aZ = mfma16(Az,Bi,aZ); aNI = mfma16(An,Bi,aNI);
        }
        if (ph > 1) {
          #pragma unroll
          for (int kt = 0; kt < 16; ++kt) {
            short8 Bh = *(const short8*)(h0P + kt*32);
            short8 Ar = *(const short8*)&sm.c0.wgh[((0*16+kt)*64+lane)*8];
            short8 Az = *(const short8*)&sm.c0.wgh[((1*16+kt)*64+lane)*8];
            short8 An = *(const short8*)&sm.c0.wgh[((2*16+kt)*64+lane)*8];
            aR = mfma16(Ar,Bh,aR); aZ = mfma16(Az,Bh,aZ); aNH = mfma16(An,Bh,aNH);
          }
        }
        unsigned short hb[4];
        #pragma unroll
        for (int r = 0; r < 4; ++r) {
          float rg = sigm(aR[r] + biasR[r]);
          float zg = sigm(aZ[r] + biasZ[r]);
          float ng = tanhfast(aNI[r] + biasNI[r] + rg*(aNH[r] + biasNH[r]));
          float hn = (1.f - zg)*ng + zg*hloc[r];
          hloc[r] = hn; hb[r] = f2bf(hn);
        }
        unsigned short* dst = H0 + ((long)(ph & 1)*128 + bg)*512 + 16*su + 4*quad;
        uint2 pk; pk.x = hb[0] | ((unsigned)hb[1] << 16); pk.y = hb[2] | ((unsigned)hb[3] << 16);
        *(uint2*)dst = pk;
      }
      if (isSoft && ph >= 4) {     // online softmax, t_s = ph-4 (16 thr/batch x 32 dims)
        int ts = ph - 4;
        float s = 0.f;
        if ((tid & 15) == 0) s = atomicExch(&SB[(ts & 1)*128 + sb_b], 0.f);  // read+zero
        s = __shfl(s, lane & 48);
        unsigned vbit = (vb[sb_b*16 + (ts >> 5)] >> (ts & 31)) & 1u;
        if (vbit) {
          float Mn = fmaxf(softM, s);
          float al = __expf(softM - Mn);
          float e  = __expf(s - Mn);
          const unsigned short* hp = H1 + ((long)((ts+2) & 3)*128 + sb_b)*512 + sd0;
          softDen = softDen*al + e;
          #pragma unroll
          for (int v = 0; v < 4; ++v) {
            short8 hv = *(const short8*)(hp + v*8);
            #pragma unroll
            for (int ee = 0; ee < 8; ++ee)
              num[v*8+ee] = num[v*8+ee]*al + e*bf2f((unsigned short)hv[ee]);
          }
          softM = Mn;
        }
      }
    } else {
      if (ph >= 2 && ph <= 513) {  // cell1 step t1 = ph-2, full K per wave
        int t1 = ph - 2;
        int parH = (ph-1) & 1, parH1 = (ph-1) & 3;
        const unsigned short* h0P = H0 + ((long)parH*128 + bg)*512 + quad*8;
        float dtb = dtb_n;
        if (t1 + 1 < 512) dtb_n = ldin(tau, (long)bg*512 + t1 + 1, bf);
        float4v aR={}, aZ={}, aNI={}, aNH={};
        #pragma unroll
        for (int kt = 0; kt < 16; ++kt) {
          short8 Bi = *(const short8*)(h0P + kt*32);
          short8 Ar = *(const short8*)&sm.c1.w1i[((0*16+kt)*64+lane)*8];
          short8 Az = *(const short8*)&sm.c1.w1i[((1*16+kt)*64+lane)*8];
          short8 An = *(const short8*)&sm.c1.w1i[((2*16+kt)*64+lane)*8];
          aR = mfma16(Ar,Bi,aR); aZ = mfma16(Az,Bi,aZ); aNI = mfma16(An,Bi,aNI);
        }
        if (t1 >= 1) {
          const unsigned short* h1P = H1 + ((long)parH1*128 + bg)*512 + quad*8;
          #pragma unroll
          for (int kt = 0; kt < 16; ++kt) {
            short8 hv = *(const short8*)(h1P + kt*32);
            const float* w2p = &sm.c1.w2[kt*32 + quad*8];
            short8 Bh;
            #pragma unroll
            for (int e = 0; e < 8; ++e) {
              float f = bf2f((unsigned short)hv[e]) * exp2f(-dtb * w2p[e]);
              Bh[e] = (short)f2bf(f);
            }
            short8 Ar = *(const short8*)&sm.c1.w1h[((0*16+kt)*64+lane)*8];
            short8 Az = *(const short8*)&sm.c1.w1h[((1*16+kt)*64+lane)*8];
            short8 An = *(const short8*)&sm.c1.w1h[((2*16+kt)*64+lane)*8];
            aR = mfma16(Ar,Bh,aR); aZ = mfma16(Az,Bh,aZ); aNH = mfma16(An,Bh,aNH);
          }
        }
        unsigned short hb[4];
        #pragma unroll
        for (int r = 0; r < 4; ++r) {
          float rg = sigm(aR[r] + biasR[r]);
          float zg = sigm(aZ[r] + biasZ[r]);
          float ng = tanhfast(aNI[r] + biasNI[r] + rg*(aNH[r] + biasNH[r]));
          float h1d = exp2f(-dtb * w2own[r]) * hloc[r];
          float hn = (1.f - zg)*ng + zg*h1d;
          hloc[r] = hn; hb[r] = f2bf(hn);
        }
        unsigned short* dst = H1 + ((long)(ph & 3)*128 + bg)*512 + 16*su + 4*quad;
        uint2 pk; pk.x = hb[0] | ((unsigned)hb[1] << 16); pk.y = hb[2] | ((unsigned)hb[3] << 16);
        *(uint2*)dst = pk;
      }
      if (isPool && ph >= 3 && ph <= 514) {   // pool partial, t = ph-3
        int t = ph - 3, parP = (ph-1) & 3;
        const unsigned short* hP = H1 + ((long)parP*128 + bg)*512 + quad*8;
        float4v pa = {};
        #pragma unroll
        for (int kt = 0; kt < 16; ++kt) {
          short8 Bv = *(const short8*)(hP + kt*32);
          short8 Av = *(const short8*)&sm.c1.pwl[(kt*64+lane)*8];
          pa = mfma16(Av, Bv, pa);
        }
        float part = 0.f;
        #pragma unroll
        for (int r = 0; r < 4; ++r)
          part += sm.c1.pul[4*quad+r] * tanhfast(pa[r] + sm.c1.pbl[4*quad+r]);
        part += __shfl_down(part, 32);
        part += __shfl_down(part, 16);
        if (lane < 16) atomicAdd(&SB[(t & 1)*128 + bg], part);
      }
    }
    gbar(myctr, tid, 64u * (unsigned)(ph + 1));
  }

  if (isSoft) {   // heads: z = num/den; mort = z@mw.T + mb, los = z@lw.T + lb  (f32 out)
    float invd = 1.f / fmaxf(softDen, 1e-30f);
    float m0 = 0.f, m1 = 0.f, l0 = 0.f;
    #pragma unroll
    for (int j = 0; j < 32; ++j) {
      float z = num[j] * invd;
      m0 += z * ldin(mw, sd0 + j, bf);
      m1 += z * ldin(mw, 512 + sd0 + j, bf);
      l0 += z * ldin(lw, sd0 + j, bf);
    }
    for (int off = 8; off; off >>= 1) {
      m0 += __shfl_down(m0, off, 16);
      m1 += __shfl_down(m1, off, 16);
      l0 += __shfl_down(l0, off, 16);
    }
    if ((tid & 15) == 0) {
      out[2*sb_b]     = m0 + ldin(mb, 0, bf);
      out[2*sb_b + 1] = m1 + ldin(mb, 1, bf);
      out[256 + sb_b] = l0 + ldin(lb, 0, bf);
    }
  }
}

extern "C" void kernel_launch(void* const* d_in, const int* in_sizes, int n_in,
                              void* d_out, int out_size, void* d_ws, size_t ws_size,
                              hipStream_t stream) {
  const void* x    = d_in[0];
  const void* tau  = d_in[1];
  const void* mask = d_in[2];
  const void* W_gx = d_in[3];
  const void* W_gh = d_in[4];
  const void* Wih0 = d_in[5];
  const void* Whh0 = d_in[6];
  const void* bih0 = d_in[7];
  const void* bhh0 = d_in[8];
  const void* Wih1 = d_in[9];
  const void* Whh1 = d_in[10];
  const void* bih1 = d_in[11];
  const void* bhh1 = d_in[12];
  const void* pW   = d_in[13];
  const void* pb   = d_in[14];
  const void* pu   = d_in[15];
  const void* mw   = d_in[16];
  const void* mb   = d_in[17];
  const void* lw   = d_in[18];
  const void* lb   = d_in[19];
  (void)in_sizes; (void)n_in; (void)out_size; (void)ws_size;
  char* ws = (char*)d_ws;
  float* outp = (float*)d_out;

  hipLaunchKernelGGL(k_detect, dim3(1), dim3(256), 0, stream, mask, ws);
  hipLaunchKernelGGL(k_prep, dim3(128), dim3(256), 0, stream, x, mask, ws);

  void* kargs[] = {
    (void*)&x, (void*)&tau, (void*)&mask, (void*)&W_gx, (void*)&W_gh,
    (void*)&Wih0, (void*)&Whh0, (void*)&bih0, (void*)&bhh0,
    (void*)&Wih1, (void*)&Whh1, (void*)&bih1, (void*)&bhh1,
    (void*)&pW, (void*)&pb, (void*)&pu, (void*)&mw, (void*)&mb,
    (void*)&lw, (void*)&lb, (void*)&ws, (void*)&outp
  };
  hipLaunchCooperativeKernel((void*)k_scan, dim3(128), dim3(256), kargs, 0, stream);
}

// Round 8
// 7176.340 us; speedup vs baseline: 1.8933x; 1.2185x over previous
//
#include <hip/hip_runtime.h>
#include <math.h>

// GRU-D (B=128, L=512, DI=128, DM=512) — MI355X persistent scan, online-softmax pooling.
// 128 coop blocks = 2 independent groups (64 batches each) x [32 cell0 + 32 cell1].
// Cross-block state (INP/H0/H1) published via relaxed AGENT atomic stores (sc1
// write-through -> L3 coherence point, no dirty L2). Barrier: s_waitcnt + relaxed
// counter + acquire-only fence (buffer_inv, no wbl2 writeback walk).
// Pipeline: inp(t)@ph=t -> c0(t)@t+1 -> c1(t)@t+2 -> pool(t)@t+3 -> soft(t)@t+4; 516 phases.

typedef __attribute__((ext_vector_type(8))) short short8;
typedef __attribute__((ext_vector_type(4))) float float4v;

#define LOG2E 1.4426950408889634f
#define FLAG_OFF 0
#define CTR_OFF  1024      // u32 ctr[g] at CTR_OFF + g*256B
#define XM_OFF   4096      // f32[128*128]
#define VB_OFF   69632     // u32[128*16]
#define INP_OFF  81920     // bf16 2par*128*256 (interleaved x/mask pairs)
#define H0_OFF   212992    // bf16 2par*128*512
#define H1_OFF   475136    // bf16 4par*128*512
#define SB_OFF   999424    // f32 2par*128

__device__ __forceinline__ unsigned short f2bf(float f) {
  unsigned u = __float_as_uint(f);
  u += 0x7fffu + ((u >> 16) & 1u);
  return (unsigned short)(u >> 16);
}
__device__ __forceinline__ float bf2f(unsigned short h) {
  return __uint_as_float(((unsigned)h) << 16);
}
__device__ __forceinline__ float ldin(const void* p, long i, int bf) {
  return bf ? bf2f(((const unsigned short*)p)[i]) : ((const float*)p)[i];
}
__device__ __forceinline__ int nanbits(float f) {
  return (__float_as_uint(f) & 0x7fffffffu) > 0x7f800000u;
}
__device__ __forceinline__ float sigm(float x){ return 1.f/(1.f+__expf(-x)); }
__device__ __forceinline__ float tanhfast(float x){ return 2.f/(1.f+__expf(-2.f*x)) - 1.f; }
__device__ __forceinline__ float4v mfma16(short8 a, short8 b, float4v c) {
  return __builtin_amdgcn_mfma_f32_16x16x32_bf16(a, b, c, 0, 0, 0);
}
// device-visible publish: relaxed agent atomic store (sc1 write-through, no L2 dirty)
__device__ __forceinline__ void pub64(void* p, unsigned long long v) {
  __hip_atomic_store((unsigned long long*)p, v, __ATOMIC_RELAXED, __HIP_MEMORY_SCOPE_AGENT);
}
__device__ __forceinline__ void pub32(void* p, unsigned v) {
  __hip_atomic_store((unsigned*)p, v, __ATOMIC_RELAXED, __HIP_MEMORY_SCOPE_AGENT);
}
// per-group barrier: drain write-through stores, relaxed counter, acquire-invalidate only
__device__ __forceinline__ void gbar(unsigned* ctr, int tid, unsigned tgt) {
  __builtin_amdgcn_s_waitcnt(0);   // all counters 0: drain this wave's sc1 stores/atomics
  __syncthreads();
  if (tid == 0) {
    __hip_atomic_fetch_add(ctr, 1u, __ATOMIC_RELAXED, __HIP_MEMORY_SCOPE_AGENT);
    while (__hip_atomic_load(ctr, __ATOMIC_RELAXED, __HIP_MEMORY_SCOPE_AGENT) < tgt)
      __builtin_amdgcn_s_sleep(1);
    __builtin_amdgcn_fence(__ATOMIC_ACQUIRE, "agent");  // buffer_inv sc1 (no wbl2)
  }
  __syncthreads();
}
// INP column permutation: LDS slot k (0..255) <- Wih0 source column
__device__ __forceinline__ int inp_perm(int k) {
  return (k & 1) ? (128 + (k >> 1)) : (k >> 1);
}

// ---------------- dtype detect + ctr zero ----------------
__global__ __launch_bounds__(256) void k_detect(const void* mask, char* ws) {
  __shared__ int sh[256];
  const unsigned* mw = (const unsigned*)mask;
  int t = threadIdx.x, bad = 0;
  for (int i = t; i < 2048; i += 256) {
    unsigned w = mw[i];
    if (w != 0u && w != 0x3F800000u) bad = 1;
  }
  sh[t] = bad; __syncthreads();
  for (int s = 128; s; s >>= 1) { if (t < s) sh[t] |= sh[t + s]; __syncthreads(); }
  if (t == 0) *(unsigned*)(ws + FLAG_OFF) = sh[0] ? 1u : 0u;
  if (t < 128) ((unsigned*)(ws + CTR_OFF))[t] = 0u;
}

// ---------------- prep: xm + valid bits ----------------
__global__ __launch_bounds__(256) void k_prep(const void* x, const void* mask, char* ws) {
  int b = blockIdx.x, tid = threadIdx.x;
  int bf = (int)*(const unsigned*)(ws + FLAG_OFF);
  float* xm = (float*)(ws + XM_OFF);
  unsigned* vb = (unsigned*)(ws + VB_OFF);
  __shared__ int va[2][512];
  int wav = tid >> 6, lane = tid & 63;
  if (tid < 128) {
    float sx = 0.f, sm = 0.f;
    for (int l = 0; l < 512; ++l) {
      long idx = ((long)b*512 + l)*128 + tid;
      float xv = ldin(x, idx, bf); if (nanbits(xv)) xv = 0.f;
      float mv = ldin(mask, idx, bf);
      sx += xv*mv; sm += mv;
      int any = (__ballot(mv > 0.f) != 0ull);
      if (lane == 0) va[wav][l] = any;
    }
    xm[b*128 + tid] = sx / fmaxf(sm, 1.f);
  }
  __syncthreads();
  if (tid < 16) {
    unsigned w = 0;
    for (int j = 0; j < 32; ++j) { int l = tid*32 + j; if (va[0][l] | va[1][l]) w |= (1u << j); }
    vb[b*16 + tid] = w;
  }
}

// ---------------- scan ----------------
struct SC0 { unsigned short wgi[3*8*64*8]; unsigned short wgh[3*16*64*8]; };           // 72 KB
struct SC1 { unsigned short w1i[3*16*64*8]; unsigned short w1h[3*16*64*8];
             unsigned short pwl[16*64*8]; float w2[512]; float pbl[16], pul[16]; };    // ~114 KB
union __align__(16) SMU { SC0 c0; SC1 c1; };

__global__ __launch_bounds__(256, 1) void k_scan(
    const void* x, const void* tau, const void* mask,
    const void* W_gx, const void* W_gh,
    const void* Wih0, const void* Whh0, const void* bih0, const void* bhh0,
    const void* Wih1, const void* Whh1, const void* bih1, const void* bhh1,
    const void* pW, const void* pb, const void* pu,
    const void* mw, const void* mb, const void* lw, const void* lb,
    char* ws, float* out)
{
  __shared__ SMU sm;
  int tid = threadIdx.x, bx = blockIdx.x;
  int g = bx & 1, role = bx >> 1;          // 2 groups of 64 batches
  int wav = tid >> 6, lane = tid & 63, quad = lane >> 4, l15 = lane & 15;
  int bf = (int)*(const unsigned*)(ws + FLAG_OFF);
  unsigned* myctr = (unsigned*)(ws + CTR_OFF) + g*64;
  float* xm = (float*)(ws + XM_OFF);
  unsigned* vb = (unsigned*)(ws + VB_OFF);
  unsigned short* INP = (unsigned short*)(ws + INP_OFF);
  unsigned short* H0  = (unsigned short*)(ws + H0_OFF);
  unsigned short* H1  = (unsigned short*)(ws + H1_OFF);
  float* SB = (float*)(ws + SB_OFF);

  bool isC0 = (role < 32);
  int su = isC0 ? role : (role - 32);      // 16 h-dims: [16su, 16su+16)
  int bg = 64*g + 16*wav + l15;            // this lane's batch (GEMM n-dim)
  bool isSoft = isC0 && (su < 4);
  bool isPool = (!isC0) && (su < 16);

  float biasR[4], biasZ[4], biasNI[4], biasNH[4], w2own[4];
  float hloc[4] = {0.f,0.f,0.f,0.f};
  float softM = -INFINITY, softDen = 0.f;
  float num[32];
  #pragma unroll
  for (int j = 0; j < 32; ++j) num[j] = 0.f;
  int sb_b = 64*g + 16*su + (tid >> 4);    // soft: batch (su<4)
  int sd0 = (tid & 15) * 32;               // soft: dim slice base

  float xprev = 0.f, xm_r = 0.f, gxw2 = 0.f;
  int b_xi = 64*g + (tid >> 2), f_xi = 4*su + (tid & 3);   // impute mapping (c0)
  float dt_n = 0.f, xv_n = 0.f, mv_n = 0.f, dtb_n = 0.f;   // prefetch regs

  if (isC0) {
    for (int r = 0; r < 4; ++r) {
      int row = 16*su + 4*quad + r;
      biasR[r]  = ldin(bih0, row, bf) + ldin(bhh0, row, bf);
      biasZ[r]  = ldin(bih0, 512+row, bf) + ldin(bhh0, 512+row, bf);
      biasNI[r] = ldin(bih0, 1024+row, bf);
      biasNH[r] = ldin(bhh0, 1024+row, bf);
      w2own[r] = 0.f;
    }
    xm_r = xm[b_xi*128 + f_xi];
    gxw2 = fmaxf(ldin(W_gx, f_xi, bf), 0.f) * LOG2E;
    // Wih0 slice, columns permuted to match interleaved INP (x0,m0,x1,m1,...)
    for (int i = tid; i < 3*8*64; i += 256) {
      int gate = i >> 9, rr = i & 511, kt = rr >> 6, ll = rr & 63;
      int row = gate*512 + 16*su + (ll & 15);
      int k0 = kt*32 + (ll >> 4)*8;
      for (int j = 0; j < 8; ++j)
        sm.c0.wgi[i*8+j] = f2bf(ldin(Wih0, (long)row*256 + inp_perm(k0 + j), bf));
    }
    for (int i = tid; i < 3*16*64; i += 256) {
      int gate = i >> 10, rr = i & 1023, kt = rr >> 6, ll = rr & 63;
      int row = gate*512 + 16*su + (ll & 15);
      int k0 = kt*32 + (ll >> 4)*8;
      for (int j = 0; j < 8; ++j) sm.c0.wgh[i*8+j] = f2bf(ldin(Whh0, (long)row*512 + k0 + j, bf));
    }
    if (isSoft) SB[tid] = 0.f;   // zero both parities (redundant across soft blocks, same value)
    // prefetch t=0 impute inputs
    dt_n = ldin(tau, (long)b_xi*512, bf);
    long idx0 = (long)b_xi*512*128 + f_xi;
    xv_n = ldin(x, idx0, bf);
    mv_n = ldin(mask, idx0, bf);
  } else {
    for (int r = 0; r < 4; ++r) {
      int row = 16*su + 4*quad + r;
      biasR[r]  = ldin(bih1, row, bf) + ldin(bhh1, row, bf);
      biasZ[r]  = ldin(bih1, 512+row, bf) + ldin(bhh1, 512+row, bf);
      biasNI[r] = ldin(bih1, 1024+row, bf);
      biasNH[r] = ldin(bhh1, 1024+row, bf);
      w2own[r]  = fmaxf(ldin(W_gh, row, bf), 0.f) * LOG2E;
    }
    for (int i = tid; i < 3*16*64; i += 256) {
      int gate = i >> 10, rr = i & 1023, kt = rr >> 6, ll = rr & 63;
      int row = gate*512 + 16*su + (ll & 15);
      int k0 = kt*32 + (ll >> 4)*8;
      for (int j = 0; j < 8; ++j) {
        sm.c1.w1i[i*8+j] = f2bf(ldin(Wih1, (long)row*512 + k0 + j, bf));
        sm.c1.w1h[i*8+j] = f2bf(ldin(Whh1, (long)row*512 + k0 + j, bf));
      }
    }
    for (int i = tid; i < 512; i += 256) sm.c1.w2[i] = fmaxf(ldin(W_gh, i, bf), 0.f) * LOG2E;
    if (isPool) {
      for (int i = tid; i < 16*64; i += 256) {
        int kt = i >> 6, ll = i & 63;
        int row = 16*su + (ll & 15);
        int k0 = kt*32 + (ll >> 4)*8;
        for (int j = 0; j < 8; ++j) sm.c1.pwl[i*8+j] = f2bf(ldin(pW, (long)row*512 + k0 + j, bf));
      }
      if (tid < 16) { sm.c1.pbl[tid] = ldin(pb, 16*su + tid, bf); sm.c1.pul[tid] = ldin(pu, 16*su + tid, bf); }
    }
    dtb_n = ldin(tau, (long)bg*512, bf);   // prefetch t1=0
  }
  __syncthreads();

  for (int ph = 0; ph < 516; ++ph) {
    if (isC0) {
      if (ph < 512) {              // impute + publish (x_imp,mask)(t=ph) as one u32 pair
        float dt = dt_n, xv = xv_n, mv = mv_n;
        if (ph + 1 < 512) {        // prefetch t=ph+1 (latency hidden behind next barrier)
          dt_n = ldin(tau, (long)b_xi*512 + ph + 1, bf);
          long idx2 = ((long)b_xi*512 + (ph+1))*128 + f_xi;
          xv_n = ldin(x, idx2, bf);
          mv_n = ldin(mask, idx2, bf);
        }
        if (nanbits(xv)) xv = 0.f;
        float gxv = exp2f(-dt * gxw2);
        float xi = mv*xv + (1.f-mv)*(gxv*xprev + (1.f-gxv)*xm_r);
        xprev = xi;
        unsigned pv = (unsigned)f2bf(xi) | ((unsigned)f2bf(mv) << 16);
        pub32((unsigned*)(INP + ((long)(ph & 1)*128 + b_xi)*256) + f_xi, pv);
      }
      if (ph >= 1 && ph <= 512) {  // cell0 step t0 = ph-1, full K per wave
        int parR = (ph-1) & 1;
        const unsigned short* inpP = INP + ((long)parR*128 + bg)*256 + quad*8;
        const unsigned short* h0P  = H0 + ((long)parR*128 + bg)*512 + quad*8;
        float4v aR={}, aZ={}, aNI={}, aNH={};
        #pragma unroll
        for (int kt = 0; kt < 8; ++kt) {
          short8 Bi = *(const short8*)(inpP + kt*32);
          short8 Ar = *(const short8*)&sm.c0.wgi[((0*8+kt)*64+lane)*8];
          short8 Az = *(const short8*)&sm.c0.wgi[((1*8+kt)*64+lane)*8];
          short8 An = *(const short8*)&sm.c0.wgi[((2*8+kt)*64+lane)*8];
          aR = mfma16(Ar,Bi,aR); aZ = mfma16(Az,Bi,aZ); aNI = mfma16(An,Bi,aNI);
        }
        if (ph > 1) {
          #pragma unroll
          for (int kt = 0; kt < 16; ++kt) {
            short8 Bh = *(const short8*)(h0P + kt*32);
            short8 Ar = *(const short8*)&sm.c0.wgh[((0*16+kt)*64+lane)*8];
            short8 Az = *(const short8*)&sm.c0.wgh[((1*16+kt)*64+lane)*8];
            short8 An = *(const short8*)&sm.c0.wgh[((2*16+kt)*64+lane)*8];
            aR = mfma16(Ar,Bh,aR); aZ = mfma16(Az,Bh,aZ); aNH = mfma16(An,Bh,aNH);
          }
        }
        unsigned short hb[4];
        #pragma unroll
        for (int r = 0; r < 4; ++r) {
          float rg = sigm(aR[r] + biasR[r]);
          float zg = sigm(aZ[r] + biasZ[r]);
          float ng = tanhfast(aNI[r] + biasNI[r] + rg*(aNH[r] + biasNH[r]));
          float hn = (1.f - zg)*ng + zg*hloc[r];
          hloc[r] = hn; hb[r] = f2bf(hn);
        }
        unsigned short* dst = H0 + ((long)(ph & 1)*128 + bg)*512 + 16*su + 4*quad;
        unsigned long long pk64 = (unsigned long long)(hb[0] | ((unsigned)hb[1] << 16))
                                | ((unsigned long long)(hb[2] | ((unsigned)hb[3] << 16)) << 32);
        pub64(dst, pk64);
      }
      if (isSoft && ph >= 4) {     // online softmax, t_s = ph-4 (16 thr/batch x 32 dims)
        int ts = ph - 4;
        float s = 0.f;
        if ((tid & 15) == 0) s = atomicExch(&SB[(ts & 1)*128 + sb_b], 0.f);  // read+zero
        s = __shfl(s, lane & 48);
        unsigned vbit = (vb[sb_b*16 + (ts >> 5)] >> (ts & 31)) & 1u;
        if (vbit) {
          float Mn = fmaxf(softM, s);
          float al = __expf(softM - Mn);
          float e  = __expf(s - Mn);
          const unsigned short* hp = H1 + ((long)((ts+2) & 3)*128 + sb_b)*512 + sd0;
          softDen = softDen*al + e;
          #pragma unroll
          for (int v = 0; v < 4; ++v) {
            short8 hv = *(const short8*)(hp + v*8);
            #pragma unroll
            for (int ee = 0; ee < 8; ++ee)
              num[v*8+ee] = num[v*8+ee]*al + e*bf2f((unsigned short)hv[ee]);
          }
          softM = Mn;
        }
      }
    } else {
      if (ph >= 2 && ph <= 513) {  // cell1 step t1 = ph-2, full K per wave
        int t1 = ph - 2;
        int parH = (ph-1) & 1, parH1 = (ph-1) & 3;
        const unsigned short* h0P = H0 + ((long)parH*128 + bg)*512 + quad*8;
        float dtb = dtb_n;
        if (t1 + 1 < 512) dtb_n = ldin(tau, (long)bg*512 + t1 + 1, bf);
        float4v aR={}, aZ={}, aNI={}, aNH={};
        #pragma unroll
        for (int kt = 0; kt < 16; ++kt) {
          short8 Bi = *(const short8*)(h0P + kt*32);
          short8 Ar = *(const short8*)&sm.c1.w1i[((0*16+kt)*64+lane)*8];
          short8 Az = *(const short8*)&sm.c1.w1i[((1*16+kt)*64+lane)*8];
          short8 An = *(const short8*)&sm.c1.w1i[((2*16+kt)*64+lane)*8];
          aR = mfma16(Ar,Bi,aR); aZ = mfma16(Az,Bi,aZ); aNI = mfma16(An,Bi,aNI);
        }
        if (t1 >= 1) {
          const unsigned short* h1P = H1 + ((long)parH1*128 + bg)*512 + quad*8;
          #pragma unroll
          for (int kt = 0; kt < 16; ++kt) {
            short8 hv = *(const short8*)(h1P + kt*32);
            const float* w2p = &sm.c1.w2[kt*32 + quad*8];
            short8 Bh;
            #pragma unroll
            for (int e = 0; e < 8; ++e) {
              float f = bf2f((unsigned short)hv[e]) * exp2f(-dtb * w2p[e]);
              Bh[e] = (short)f2bf(f);
            }
            short8 Ar = *(const short8*)&sm.c1.w1h[((0*16+kt)*64+lane)*8];
            short8 Az = *(const short8*)&sm.c1.w1h[((1*16+kt)*64+lane)*8];
            short8 An = *(const short8*)&sm.c1.w1h[((2*16+kt)*64+lane)*8];
            aR = mfma16(Ar,Bh,aR); aZ = mfma16(Az,Bh,aZ); aNH = mfma16(An,Bh,aNH);
          }
        }
        unsigned short hb[4];
        #pragma unroll
        for (int r = 0; r < 4; ++r) {
          float rg = sigm(aR[r] + biasR[r]);
          float zg = sigm(aZ[r] + biasZ[r]);
          float ng = tanhfast(aNI[r] + biasNI[r] + rg*(aNH[r] + biasNH[r]));
          float h1d = exp2f(-dtb * w2own[r]) * hloc[r];
          float hn = (1.f - zg)*ng + zg*h1d;
          hloc[r] = hn; hb[r] = f2bf(hn);
        }
        unsigned short* dst = H1 + ((long)(ph & 3)*128 + bg)*512 + 16*su + 4*quad;
        unsigned long long pk64 = (unsigned long long)(hb[0] | ((unsigned)hb[1] << 16))
                                | ((unsigned long long)(hb[2] | ((unsigned)hb[3] << 16)) << 32);
        pub64(dst, pk64);
      }
      if (isPool && ph >= 3 && ph <= 514) {   // pool partial, t = ph-3
        int t = ph - 3, parP = (ph-1) & 3;
        const unsigned short* hP = H1 + ((long)parP*128 + bg)*512 + quad*8;
        float4v pa = {};
        #pragma unroll
        for (int kt = 0; kt < 16; ++kt) {
          short8 Bv = *(const short8*)(hP + kt*32);
          short8 Av = *(const short8*)&sm.c1.pwl[(kt*64+lane)*8];
          pa = mfma16(Av, Bv, pa);
        }
        float part = 0.f;
        #pragma unroll
        for (int r = 0; r < 4; ++r)
          part += sm.c1.pul[4*quad+r] * tanhfast(pa[r] + sm.c1.pbl[4*quad+r]);
        part += __shfl_down(part, 32);
        part += __shfl_down(part, 16);
        if (lane < 16) atomicAdd(&SB[(t & 1)*128 + bg], part);
      }
    }
    gbar(myctr, tid, 64u * (unsigned)(ph + 1));
  }

  if (isSoft) {   // heads: z = num/den; mort = z@mw.T + mb, los = z@lw.T + lb  (f32 out)
    float invd = 1.f / fmaxf(softDen, 1e-30f);
    float m0 = 0.f, m1 = 0.f, l0 = 0.f;
    #pragma unroll
    for (int j = 0; j < 32; ++j) {
      float z = num[j] * invd;
      m0 += z * ldin(mw, sd0 + j, bf);
      m1 += z * ldin(mw, 512 + sd0 + j, bf);
      l0 += z * ldin(lw, sd0 + j, bf);
    }
    for (int off = 8; off; off >>= 1) {
      m0 += __shfl_down(m0, off, 16);
      m1 += __shfl_down(m1, off, 16);
      l0 += __shfl_down(l0, off, 16);
    }
    if ((tid & 15) == 0) {
      out[2*sb_b]     = m0 + ldin(mb, 0, bf);
      out[2*sb_b + 1] = m1 + ldin(mb, 1, bf);
      out[256 + sb_b] = l0 + ldin(lb, 0, bf);
    }
  }
}

extern "C" void kernel_launch(void* const* d_in, const int* in_sizes, int n_in,
                              void* d_out, int out_size, void* d_ws, size_t ws_size,
                              hipStream_t stream) {
  const void* x    = d_in[0];
  const void* tau  = d_in[1];
  const void* mask = d_in[2];
  const void* W_gx = d_in[3];
  const void* W_gh = d_in[4];
  const void* Wih0 = d_in[5];
  const void* Whh0 = d_in[6];
  const void* bih0 = d_in[7];
  const void* bhh0 = d_in[8];
  const void* Wih1 = d_in[9];
  const void* Whh1 = d_in[10];
  const void* bih1 = d_in[11];
  const void* bhh1 = d_in[12];
  const void* pW   = d_in[13];
  const void* pb   = d_in[14];
  const void* pu   = d_in[15];
  const void* mw   = d_in[16];
  const void* mb   = d_in[17];
  const void* lw   = d_in[18];
  const void* lb   = d_in[19];
  (void)in_sizes; (void)n_in; (void)out_size; (void)ws_size;
  char* ws = (char*)d_ws;
  float* outp = (float*)d_out;

  hipLaunchKernelGGL(k_detect, dim3(1), dim3(256), 0, stream, mask, ws);
  hipLaunchKernelGGL(k_prep, dim3(128), dim3(256), 0, stream, x, mask, ws);

  void* kargs[] = {
    (void*)&x, (void*)&tau, (void*)&mask, (void*)&W_gx, (void*)&W_gh,
    (void*)&Wih0, (void*)&Whh0, (void*)&bih0, (void*)&bhh0,
    (void*)&Wih1, (void*)&Whh1, (void*)&bih1, (void*)&bhh1,
    (void*)&pW, (void*)&pb, (void*)&pu, (void*)&mw, (void*)&mb,
    (void*)&lw, (void*)&lb, (void*)&ws, (void*)&outp
  };
  hipLaunchCooperativeKernel((void*)k_scan, dim3(128), dim3(256), kargs, 0, stream);
}